// Round 18
// baseline (597.706 us; speedup 1.0000x reference)
//
#include <hip/hip_runtime.h>

typedef unsigned short u16;
typedef __attribute__((ext_vector_type(8))) short bf16x8;
typedef __attribute__((ext_vector_type(8))) unsigned short u16x8;
typedef __attribute__((ext_vector_type(16))) float f32x16;

#define NTOK 8192
#define CDIM 1024
#define EXP 8
#define HDIM 2752
#define HPAD 2816
#define CAPQ 2560
#define MAXROWS 18432

__device__ __forceinline__ u16 f2bu(float f) {
    unsigned u = __float_as_uint(f);
    u += 0x7fffu + ((u >> 16) & 1u);
    return (u16)(u >> 16);
}
__device__ __forceinline__ float b2f(u16 s) {
    return __uint_as_float(((unsigned)s) << 16);
}

__device__ __forceinline__ void gl_lds16(const u16* g, u16* l) {
    __builtin_amdgcn_global_load_lds(
        (const __attribute__((address_space(1))) unsigned int*)g,
        (__attribute__((address_space(3))) unsigned int*)l, 16, 0, 0);
}

// ---------------- K0: zero loss accumulators + blkCnt ----------------
__global__ void k_zero(float* p, int* blkCnt) {
    if (threadIdx.x < 32) p[threadIdx.x] = 0.f;
    int i = (int)threadIdx.x - 32;
    if (i >= 0 && i < 512) blkCnt[i] = 0;
}

// ---- K1: merged front: trans (0..16895) | router (16896..18943) | zero-out
__global__ __launch_bounds__(256) void k_front(const float* __restrict__ x,
                                               const float* __restrict__ Wr,
                                               const float* __restrict__ Wg,
                                               const float* __restrict__ Wu,
                                               const float* __restrict__ Wd,
                                               int* __restrict__ top2i,
                                               float* __restrict__ top2v,
                                               float* __restrict__ lossf,
                                               int* __restrict__ ce,
                                               int* __restrict__ blkCnt,
                                               u16* __restrict__ WgT,
                                               u16* __restrict__ WuT,
                                               u16* __restrict__ WdT,
                                               float* __restrict__ outz) {
    const int bz = blockIdx.x;
    const int tid = threadIdx.x;
    if (bz < 16896) {
        __shared__ float t[64][65];
        const int zi = bz / 704;
        const int rem = bz - zi * 704;
        const int hx = rem % 44, cy = rem / 44;
        const int hb = hx * 64, cb = cy * 64;
        const bool live = (hb < HDIM);
        if (zi < 16) {
            const float* in = (zi < 8) ? Wg + (size_t)zi * CDIM * HDIM
                                       : Wu + (size_t)(zi - 8) * CDIM * HDIM;
            u16* out = (zi < 8) ? WgT + (size_t)zi * HPAD * CDIM
                                : WuT + (size_t)(zi - 8) * HPAD * CDIM;
#pragma unroll
            for (int it = 0; it < 4; it++) {
                int idx = it * 256 + tid;
                int cl = idx >> 4;
                int h4 = (idx & 15) * 4;
                float4 v = live ? *(const float4*)(in + (size_t)(cb + cl) * HDIM + hb + h4)
                                : make_float4(0.f, 0.f, 0.f, 0.f);
                t[h4 + 0][cl] = v.x;
                t[h4 + 1][cl] = v.y;
                t[h4 + 2][cl] = v.z;
                t[h4 + 3][cl] = v.w;
            }
            __syncthreads();
#pragma unroll
            for (int it = 0; it < 2; it++) {
                int idx = it * 256 + tid;
                int hl = idx >> 3;
                int c8 = (idx & 7) * 8;
                u16x8 v;
#pragma unroll
                for (int j = 0; j < 8; j++) v[j] = f2bu(t[hl][c8 + j]);
                *(u16x8*)(out + (size_t)(hb + hl) * CDIM + cb + c8) = v;
            }
        } else {
            int e = zi - 16;
            const float* in = Wd + (size_t)e * HDIM * CDIM;
            u16* out = WdT + (size_t)e * CDIM * HPAD;
#pragma unroll
            for (int it = 0; it < 4; it++) {
                int idx = it * 256 + tid;
                int hl = idx >> 4;
                int c4 = (idx & 15) * 4;
                float4 v = live ? *(const float4*)(in + (size_t)(hb + hl) * CDIM + cb + c4)
                                : make_float4(0.f, 0.f, 0.f, 0.f);
                t[c4 + 0][hl] = v.x;
                t[c4 + 1][hl] = v.y;
                t[c4 + 2][hl] = v.z;
                t[c4 + 3][hl] = v.w;
            }
            __syncthreads();
#pragma unroll
            for (int it = 0; it < 2; it++) {
                int idx = it * 256 + tid;
                int cl = idx >> 3;
                int h8 = (idx & 7) * 8;
                u16x8 v;
#pragma unroll
                for (int j = 0; j < 8; j++) v[j] = f2bu(t[cl][h8 + j]);
                *(u16x8*)(out + (size_t)(cb + cl) * HPAD + hb + h8) = v;
            }
        }
    } else if (bz < 18944) {
        __shared__ float s_me[8];
        __shared__ float s_z;
        __shared__ int s_ce[8];
        if (tid < 8) s_me[tid] = 0.f;
        if (tid == 8) s_z = 0.f;
        if (tid >= 16 && tid < 24) s_ce[tid - 16] = 0;
        __syncthreads();

        int wv = tid >> 6, lane = tid & 63;
        int tok = (bz - 16896) * 4 + wv;
        const float* xr = x + (size_t)tok * CDIM;

        float acc[8];
#pragma unroll
        for (int e = 0; e < 8; e++) acc[e] = 0.f;
#pragma unroll
        for (int j = 0; j < 16; j++) {
            int c = j * 64 + lane;
            float xv = xr[c];
            const float4 w0 = *(const float4*)(Wr + c * 8);
            const float4 w1 = *(const float4*)(Wr + c * 8 + 4);
            acc[0] = fmaf(xv, w0.x, acc[0]);
            acc[1] = fmaf(xv, w0.y, acc[1]);
            acc[2] = fmaf(xv, w0.z, acc[2]);
            acc[3] = fmaf(xv, w0.w, acc[3]);
            acc[4] = fmaf(xv, w1.x, acc[4]);
            acc[5] = fmaf(xv, w1.y, acc[5]);
            acc[6] = fmaf(xv, w1.z, acc[6]);
            acc[7] = fmaf(xv, w1.w, acc[7]);
        }
#pragma unroll
        for (int off = 32; off >= 1; off >>= 1) {
#pragma unroll
            for (int e = 0; e < 8; e++) acc[e] += __shfl_xor(acc[e], off, 64);
        }
        float mx = acc[0];
#pragma unroll
        for (int e = 1; e < 8; e++) mx = fmaxf(mx, acc[e]);
        float g[8];
        float se = 0.f;
#pragma unroll
        for (int e = 0; e < 8; e++) {
            g[e] = __expf(acc[e] - mx);
            se += g[e];
        }
        float inv = 1.f / se;
#pragma unroll
        for (int e = 0; e < 8; e++) g[e] *= inv;
        int i1 = 0;
#pragma unroll
        for (int e = 1; e < 8; e++)
            if (acc[e] > acc[i1]) i1 = e;
        int i2 = -1;
#pragma unroll
        for (int e = 0; e < 8; e++) {
            if (e == i1) continue;
            if (i2 < 0 || acc[e] > acc[i2]) i2 = e;
        }
        float zp = 0.f;
#pragma unroll
        for (int e = 0; e < 8; e++) zp = fmaf(acc[e], acc[e], zp);

        if (lane == 0) {
            top2i[tok * 2 + 0] = i1;
            top2i[tok * 2 + 1] = i2;
            top2v[tok * 2 + 0] = g[i1];
            top2v[tok * 2 + 1] = g[i2];
            atomicAdd(&s_z, zp);
            atomicAdd(&s_ce[i1], 1);
            atomicAdd(&blkCnt[(tok >> 8) * 16 + i1], 1);
            atomicAdd(&blkCnt[(tok >> 8) * 16 + 8 + i2], 1);
#pragma unroll
            for (int e = 0; e < 8; e++) atomicAdd(&s_me[e], g[e]);
        }
        __syncthreads();
        if (tid < 8) atomicAdd(&lossf[tid], s_me[tid]);
        if (tid == 8) atomicAdd(&lossf[8], s_z);
        if (tid >= 16 && tid < 24) atomicAdd(&ce[tid - 16], s_ce[tid - 16]);
    } else {
        int blk = bz - 18944;
        float4* p = (float4*)(outz) + (size_t)blk * 2048 + tid;
        float4 z = make_float4(0.f, 0.f, 0.f, 0.f);
#pragma unroll
        for (int j = 0; j < 8; j++) p[j * 256] = z;
    }
}

// ---------------- K3: prefix over blocks + expert meta ----------------
__global__ void k_prefix(const int* __restrict__ blkCnt, int* __restrict__ blkBase,
                         int* __restrict__ meta) {
    int p = threadIdx.x;
    int run = 0;
    if (p < 16) {
        for (int b = 0; b < 32; b++) {
            int v = blkCnt[b * 16 + p];
            blkBase[b * 16 + p] = run;
            run += v;
        }
    }
    int kept = run < CAPQ ? run : CAPQ;
    int k0e[8], k1e[8];
#pragma unroll
    for (int e = 0; e < 8; e++) {
        k0e[e] = __shfl(kept, e, 64);
        k1e[e] = __shfl(kept, 8 + e, 64);
    }
    if (p == 0) {
        int acc = 0;
        for (int e = 0; e < 8; e++) {
            int m = k0e[e] + k1e[e];
            int mp = (m + 255) & ~255;
            meta[e] = k0e[e];
            meta[8 + e] = k1e[e];
            meta[16 + e] = m;
            meta[24 + e] = mp;
            meta[32 + e] = acc;
            acc += mp;
        }
        meta[40] = acc;
    }
}

// ---------------- K4: per-token FIFO position, row assignment -------------
__global__ __launch_bounds__(256) void k_assign(const int* __restrict__ top2i,
                                                const int* __restrict__ blkBase,
                                                const int* __restrict__ meta,
                                                int* __restrict__ rowTok) {
    __shared__ int wcnt[4][16];
    int tid = threadIdx.x, w = tid >> 6, lane = tid & 63;
    int i = blockIdx.x * 256 + tid;
    int e0 = top2i[2 * i], e1 = top2i[2 * i + 1];
    unsigned long long m0 = 0, m1 = 0;
#pragma unroll
    for (int ex = 0; ex < 8; ex++) {
        unsigned long long b0 = __ballot(e0 == ex);
        unsigned long long b1 = __ballot(e1 == ex);
        if (e0 == ex) m0 = b0;
        if (e1 == ex) m1 = b1;
        if (lane == ex) {
            wcnt[w][ex] = __popcll(b0);
            wcnt[w][8 + ex] = __popcll(b1);
        }
    }
    __syncthreads();
    unsigned long long lt = (1ull << lane) - 1ull;
    int pos0 = blkBase[blockIdx.x * 16 + e0] + __popcll(m0 & lt);
    int pos1 = blkBase[blockIdx.x * 16 + 8 + e1] + __popcll(m1 & lt);
    for (int w2 = 0; w2 < w; w2++) {
        pos0 += wcnt[w2][e0];
        pos1 += wcnt[w2][8 + e1];
    }
    if (pos0 < CAPQ) rowTok[meta[32 + e0] + pos0] = i;
    if (pos1 < CAPQ) rowTok[meta[32 + e1] + meta[e1] + pos1] = i;
}

// ---------------- K5: gather token rows -> compact A (bf16) ---------------
__global__ __launch_bounds__(256) void k_gather(const float* __restrict__ x,
                                                const int* __restrict__ meta,
                                                const int* __restrict__ rowTok,
                                                u16* __restrict__ A) {
    int row = blockIdx.x * 4 + (threadIdx.x >> 6);
    int lane = threadIdx.x & 63;
    if (row >= meta[40]) return;
    int e = 0;
#pragma unroll
    for (int t = 1; t < 8; t++)
        if (row >= meta[32 + t]) e = t;
    int r = row - meta[32 + e];
    u16* dst = A + (size_t)row * CDIM;
    if (r >= meta[16 + e]) {
        ushort4 zz = make_ushort4(0, 0, 0, 0);
#pragma unroll
        for (int j = 0; j < 4; j++) *(ushort4*)(dst + j * 256 + lane * 4) = zz;
        return;
    }
    int tok = rowTok[row];
    const float* src = x + (size_t)tok * CDIM;
#pragma unroll
    for (int j = 0; j < 4; j++) {
        int c = j * 256 + lane * 4;
        float4 v = *(const float4*)(src + c);
        ushort4 p = make_ushort4(f2bu(v.x), f2bu(v.y), f2bu(v.z), f2bu(v.w));
        *(ushort4*)(dst + c) = p;
    }
}

// === 3-buf single-barrier GEMMs, BK=32, counted vmcnt, r3-class swizzle ===
// Per tile: vmcnt(N) -> s_barrier -> stage(t+2 into buf (t+2)%3) -> reads+MFMA.
// Buf (t+2)%3 was read at tile t-1; barrier proves all waves done with it.
// Swizzle ([*][32] u16, 64B rows): phys slot = log ^ ((row>>1)&3), both sides.

// ---------------- K7: fused gate/up GEMM + SiLU*U -> hgu bf16 -------------
// BM=256 BN=128{G|U}; LDS 3 x (A 16K + B 16K) = 96 KiB; 8 waves.
__global__ __launch_bounds__(512, 2) void k_gemm_gu(const u16* __restrict__ A,
                                                    const u16* __restrict__ Bg,
                                                    const u16* __restrict__ Bu,
                                                    u16* __restrict__ HGU,
                                                    const int* __restrict__ meta) {
    const int e = blockIdx.z;
    const int mPad = meta[24 + e];
    if ((int)(blockIdx.y * 256) >= mPad) return;
    const size_t row0 = (size_t)meta[32 + e] + (size_t)blockIdx.y * 256;
    const int col0 = blockIdx.x * 128;

    const u16* Ab = A + row0 * CDIM;
    const u16* Gb = Bg + ((size_t)e * HPAD + col0) * CDIM;
    const u16* Ub = Bu + ((size_t)e * HPAD + col0) * CDIM;

    __shared__ u16 sm[49152];  // 3 bufs x 16384 u16 (A 8192 | B 8192)

    const int tid = threadIdx.x;
    const int lane = tid & 63, w = tid >> 6;
    const int rg = w & 3, cg = w >> 2;
    const int l31 = lane & 31, sl2 = lane >> 5;
    const int srow = lane >> 2;                 // row-in-chunk 0..15
    const int sswz = ((lane & 3) ^ ((lane >> 3) & 3)) * 8;
    int ph[2];
#pragma unroll
    for (int ks = 0; ks < 2; ks++)
        ph[ks] = (((ks * 2 + sl2) ^ ((l31 >> 1) & 3)) * 8);
    const int aoff = (rg * 64 + l31) * 32;
    const int boff = (cg * 64 + l31) * 32;

    auto stage = [&](int buf, int t) {
#pragma unroll
        for (int j = 0; j < 2; ++j) {
            const int ca = w * 2 + j;           // 0..15
            gl_lds16(Ab + (size_t)(ca * 16 + srow) * CDIM + t * 32 + sswz,
                     sm + buf * 16384 + ca * 512);
        }
#pragma unroll
        for (int j = 0; j < 2; ++j) {
            const int cb = w * 2 + j;
            const u16* src = (cb < 8)
                ? Gb + (size_t)(cb * 16 + srow) * CDIM
                : Ub + (size_t)((cb - 8) * 16 + srow) * CDIM;
            gl_lds16(src + t * 32 + sswz, sm + buf * 16384 + 8192 + cb * 512);
        }
    };

    f32x16 zz = {0.f, 0.f, 0.f, 0.f, 0.f, 0.f, 0.f, 0.f,
                 0.f, 0.f, 0.f, 0.f, 0.f, 0.f, 0.f, 0.f};
    f32x16 aG[2][2], aU[2][2];
#pragma unroll
    for (int mi = 0; mi < 2; mi++)
#pragma unroll
        for (int ni = 0; ni < 2; ni++) {
            aG[mi][ni] = zz;
            aU[mi][ni] = zz;
        }

    const int NT = CDIM / 32;  // 32
    stage(0, 0);
    stage(1, 1);
    int bt = 2;  // buffer index for t+2 staging: (t+2)%3, starts at 2
    for (int t = 0; t < NT; ++t) {
        if (t < NT - 1) asm volatile("s_waitcnt vmcnt(4)" ::: "memory");
        else asm volatile("s_waitcnt vmcnt(0)" ::: "memory");
        __builtin_amdgcn_s_barrier();
        if (t + 2 < NT) stage(bt, t + 2);
        const int bc = (bt + 1) % 3;  // current buf = (t)%3 = (bt+1)%3
        const u16* pA = sm + bc * 16384;
        const u16* pB = pA + 8192;
        bf16x8 af[2][2];
#pragma unroll
        for (int mi = 0; mi < 2; mi++)
#pragma unroll
            for (int ks = 0; ks < 2; ks++)
                af[mi][ks] = *(const bf16x8*)(pA + aoff + mi * 1024 + ph[ks]);
#pragma unroll
        for (int ks = 0; ks < 2; ks++) {
            bf16x8 bg0 = *(const bf16x8*)(pB + boff + ph[ks]);
            bf16x8 bg1 = *(const bf16x8*)(pB + boff + 1024 + ph[ks]);
            bf16x8 bu0 = *(const bf16x8*)(pB + 4096 + boff + ph[ks]);
            bf16x8 bu1 = *(const bf16x8*)(pB + 4096 + boff + 1024 + ph[ks]);
#pragma unroll
            for (int mi = 0; mi < 2; mi++) {
                aG[mi][0] = __builtin_amdgcn_mfma_f32_32x32x16_bf16(af[mi][ks], bg0, aG[mi][0], 0, 0, 0);
                aG[mi][1] = __builtin_amdgcn_mfma_f32_32x32x16_bf16(af[mi][ks], bg1, aG[mi][1], 0, 0, 0);
                aU[mi][0] = __builtin_amdgcn_mfma_f32_32x32x16_bf16(af[mi][ks], bu0, aU[mi][0], 0, 0, 0);
                aU[mi][1] = __builtin_amdgcn_mfma_f32_32x32x16_bf16(af[mi][ks], bu1, aU[mi][1], 0, 0, 0);
            }
        }
        bt = bc == 2 ? 0 : bc + 1;  // wrong? bt should advance to (t+3)%3 = old (t)%3... see below
        bt = (bt + 2) % 3;          // net: bt_{t+1} = (bt_t + 1) % 3
    }

    u16* Ob = HGU + row0 * HPAD + col0;
    const int ro = rg * 64, co = cg * 64;
#pragma unroll
    for (int mi = 0; mi < 2; mi++)
#pragma unroll
        for (int ni = 0; ni < 2; ni++)
#pragma unroll
            for (int r = 0; r < 16; r++) {
                const int rr = ro + mi * 32 + (r & 3) + 8 * (r >> 2) + 4 * sl2;
                const int cc = co + ni * 32 + l31;
                float gg = aG[mi][ni][r];
                float uu = aU[mi][ni][r];
                float v = (gg / (1.f + __expf(-gg))) * uu;
                Ob[(size_t)rr * HPAD + cc] = f2bu(v);
            }
}

// ------- K8: down GEMM BM=128 BN=128, 3-buf single-barrier, fused combine --
__global__ __launch_bounds__(512, 4) void k_gemm_d(const u16* __restrict__ HGU,
                                                   const u16* __restrict__ Bd,
                                                   float* __restrict__ out,
                                                   const int* __restrict__ meta,
                                                   const int* __restrict__ rowTok,
                                                   const float* __restrict__ top2v) {
    const int e = blockIdx.z;
    const int mPad = meta[24 + e];
    if ((int)(blockIdx.y * 128) >= mPad) return;
    const int rbase = blockIdx.y * 128;
    const size_t row0 = (size_t)meta[32 + e] + rbase;
    const int col0 = blockIdx.x * 128;
    const int kept0 = meta[e];
    const int mlive = meta[16 + e];

    const u16* Ab = HGU + row0 * HPAD;
    const u16* Bb = Bd + ((size_t)e * CDIM + col0) * HPAD;

    __shared__ u16 sm[24576];  // 3 bufs x 8192 u16 (A 4096 | B 4096)

    const int tid = threadIdx.x;
    const int lane = tid & 63, w = tid >> 6;
    const int rg = w & 3, cg = w >> 2;
    const int l31 = lane & 31, sl2 = lane >> 5;
    const int srow = lane >> 2;
    const int sswz = ((lane & 3) ^ ((lane >> 3) & 3)) * 8;
    int ph[2];
#pragma unroll
    for (int ks = 0; ks < 2; ks++)
        ph[ks] = (((ks * 2 + sl2) ^ ((l31 >> 1) & 3)) * 8);
    const int aoff = (rg * 32 + l31) * 32;
    const int boff = (cg * 64 + l31) * 32;

    auto stage = [&](int buf, int t) {
        gl_lds16(Ab + (size_t)(w * 16 + srow) * HPAD + t * 32 + sswz,
                 sm + buf * 8192 + w * 512);
        gl_lds16(Bb + (size_t)(w * 16 + srow) * HPAD + t * 32 + sswz,
                 sm + buf * 8192 + 4096 + w * 512);
    };

    f32x16 zz = {0.f, 0.f, 0.f, 0.f, 0.f, 0.f, 0.f, 0.f,
                 0.f, 0.f, 0.f, 0.f, 0.f, 0.f, 0.f, 0.f};
    f32x16 aC[2];
    aC[0] = zz;
    aC[1] = zz;

    const int NT = HDIM / 32;  // 86
    stage(0, 0);
    stage(1, 1);
    int bt = 2;
    for (int t = 0; t < NT; ++t) {
        if (t < NT - 1) asm volatile("s_waitcnt vmcnt(2)" ::: "memory");
        else asm volatile("s_waitcnt vmcnt(0)" ::: "memory");
        __builtin_amdgcn_s_barrier();
        if (t + 2 < NT) stage(bt, t + 2);
        const int bc = (bt + 1) % 3;
        const u16* pA = sm + bc * 8192;
        const u16* pB = pA + 4096;
        bf16x8 af[2];
#pragma unroll
        for (int ks = 0; ks < 2; ks++)
            af[ks] = *(const bf16x8*)(pA + aoff + ph[ks]);
#pragma unroll
        for (int ks = 0; ks < 2; ks++) {
            bf16x8 b0 = *(const bf16x8*)(pB + boff + ph[ks]);
            bf16x8 b1 = *(const bf16x8*)(pB + boff + 1024 + ph[ks]);
            aC[0] = __builtin_amdgcn_mfma_f32_32x32x16_bf16(af[ks], b0, aC[0], 0, 0, 0);
            aC[1] = __builtin_amdgcn_mfma_f32_32x32x16_bf16(af[ks], b1, aC[1], 0, 0, 0);
        }
        bt = bc == 2 ? 0 : bc + 1;
        bt = (bt + 2) % 3;
    }

    const int ro = rg * 32, co = cg * 64;
#pragma unroll
    for (int r = 0; r < 16; r++) {
        const int rr = ro + (r & 3) + 8 * (r >> 2) + 4 * sl2;
        const int re = rbase + rr;
        if (re < mlive) {
            const int tok = rowTok[row0 + rr];
            const int k = (re >= kept0) ? 1 : 0;
            const float wgt = top2v[2 * tok + k];
            float* o = out + (size_t)tok * CDIM + col0 + co;
#pragma unroll
            for (int ni = 0; ni < 2; ni++)
                atomicAdd(o + ni * 32 + l31, wgt * aC[ni][r]);
        }
    }
}

// ---------------- K10: final scalar losses ----------------
__global__ void k_loss(const float* __restrict__ lossf, const int* __restrict__ ce,
                       float* __restrict__ out) {
    if (threadIdx.x == 0) {
        float aux = 0.f;
        for (int e = 0; e < 8; e++)
            aux += (lossf[e] / (float)NTOK) * ((float)ce[e] / (float)NTOK);
        aux *= (float)EXP;
        out[(size_t)NTOK * CDIM] = aux;
        out[(size_t)NTOK * CDIM + 1] = lossf[8] / (float)(NTOK * EXP);
    }
}

// ---------------- workspace layout ----------------
static constexpr size_t SZ_WT = (size_t)EXP * HPAD * CDIM * 2;
static constexpr size_t OFF_WGT = 0;
static constexpr size_t OFF_WUT = OFF_WGT + SZ_WT;
static constexpr size_t OFF_WDT = OFF_WUT + SZ_WT;
static constexpr size_t OFF_A = OFF_WDT + SZ_WT;
static constexpr size_t OFF_HGU = OFF_A + (size_t)MAXROWS * CDIM * 2;
static constexpr size_t OFF_T2I = OFF_HGU + (size_t)MAXROWS * HPAD * 2;
static constexpr size_t OFF_T2V = OFF_T2I + (size_t)NTOK * 2 * 4;
static constexpr size_t OFF_RTK = OFF_T2V + (size_t)NTOK * 2 * 4;
static constexpr size_t OFF_BC = OFF_RTK + (size_t)MAXROWS * 4;
static constexpr size_t OFF_BB = OFF_BC + 32 * 16 * 4;
static constexpr size_t OFF_MET = OFF_BB + 32 * 16 * 4;
static constexpr size_t OFF_LOSS = OFF_MET + 64 * 4;

extern "C" void kernel_launch(void* const* d_in, const int* in_sizes, int n_in,
                              void* d_out, int out_size, void* d_ws, size_t ws_size,
                              hipStream_t stream) {
    const float* x = (const float*)d_in[0];
    const float* Wr = (const float*)d_in[1];
    const float* Wg = (const float*)d_in[2];
    const float* Wu = (const float*)d_in[3];
    const float* Wd = (const float*)d_in[4];
    float* out = (float*)d_out;
    char* ws = (char*)d_ws;

    u16* WgT = (u16*)(ws + OFF_WGT);
    u16* WuT = (u16*)(ws + OFF_WUT);
    u16* WdT = (u16*)(ws + OFF_WDT);
    u16* Abuf = (u16*)(ws + OFF_A);
    u16* HGUb = (u16*)(ws + OFF_HGU);
    int* top2i = (int*)(ws + OFF_T2I);
    float* top2v = (float*)(ws + OFF_T2V);
    int* rowTok = (int*)(ws + OFF_RTK);
    int* blkCnt = (int*)(ws + OFF_BC);
    int* blkBase = (int*)(ws + OFF_BB);
    int* meta = (int*)(ws + OFF_MET);
    float* lossf = (float*)(ws + OFF_LOSS);
    int* ce = (int*)(ws + OFF_LOSS + 9 * 4);

    k_zero<<<1, 576, 0, stream>>>(lossf, blkCnt);
    k_front<<<19968, 256, 0, stream>>>(x, Wr, Wg, Wu, Wd, top2i, top2v, lossf, ce,
                                       blkCnt, WgT, WuT, WdT, out);
    k_prefix<<<1, 64, 0, stream>>>(blkCnt, blkBase, meta);
    k_assign<<<32, 256, 0, stream>>>(top2i, blkBase, meta, rowTok);
    k_gather<<<MAXROWS / 4, 256, 0, stream>>>(x, meta, rowTok, Abuf);
    k_gemm_gu<<<dim3(22, 20, 8), 512, 0, stream>>>(Abuf, WgT, WuT, HGUb, meta);
    k_gemm_d<<<dim3(8, 40, 8), 512, 0, stream>>>(HGUb, WdT, out, meta, rowTok, top2v);
    k_loss<<<1, 64, 0, stream>>>(lossf, ce, out);
}

// Round 19
// 558.090 us; speedup vs baseline: 1.0710x; 1.0710x over previous
//
#include <hip/hip_runtime.h>

typedef unsigned short u16;
typedef __attribute__((ext_vector_type(8))) short bf16x8;
typedef __attribute__((ext_vector_type(8))) unsigned short u16x8;
typedef __attribute__((ext_vector_type(16))) float f32x16;

#define NTOK 8192
#define CDIM 1024
#define EXP 8
#define HDIM 2752
#define HPAD 2816
#define CAPQ 2560
#define MAXROWS 18432

__device__ __forceinline__ u16 f2bu(float f) {
    unsigned u = __float_as_uint(f);
    u += 0x7fffu + ((u >> 16) & 1u);
    return (u16)(u >> 16);
}
__device__ __forceinline__ float b2f(u16 s) {
    return __uint_as_float(((unsigned)s) << 16);
}

__device__ __forceinline__ void gl_lds16(const u16* g, u16* l) {
    __builtin_amdgcn_global_load_lds(
        (const __attribute__((address_space(1))) unsigned int*)g,
        (__attribute__((address_space(3))) unsigned int*)l, 16, 0, 0);
}

// ---------------- K0: zero loss accumulators + blkCnt ----------------
__global__ void k_zero(float* p, int* blkCnt) {
    if (threadIdx.x < 32) p[threadIdx.x] = 0.f;
    int i = (int)threadIdx.x - 32;
    if (i >= 0 && i < 512) blkCnt[i] = 0;
}

// ---- K1: merged front: trans (0..16895) | router (16896..18943) | zero-out
__global__ __launch_bounds__(256) void k_front(const float* __restrict__ x,
                                               const float* __restrict__ Wr,
                                               const float* __restrict__ Wg,
                                               const float* __restrict__ Wu,
                                               const float* __restrict__ Wd,
                                               int* __restrict__ top2i,
                                               float* __restrict__ top2v,
                                               float* __restrict__ lossf,
                                               int* __restrict__ ce,
                                               int* __restrict__ blkCnt,
                                               u16* __restrict__ WgT,
                                               u16* __restrict__ WuT,
                                               u16* __restrict__ WdT,
                                               float* __restrict__ outz) {
    const int bz = blockIdx.x;
    const int tid = threadIdx.x;
    if (bz < 16896) {
        // ------- weight transpose: 44 x 16 x 24 tiles -------
        __shared__ float t[64][65];
        const int zi = bz / 704;
        const int rem = bz - zi * 704;
        const int hx = rem % 44, cy = rem / 44;
        const int hb = hx * 64, cb = cy * 64;
        const bool live = (hb < HDIM);
        if (zi < 16) {
            const float* in = (zi < 8) ? Wg + (size_t)zi * CDIM * HDIM
                                       : Wu + (size_t)(zi - 8) * CDIM * HDIM;
            u16* out = (zi < 8) ? WgT + (size_t)zi * HPAD * CDIM
                                : WuT + (size_t)(zi - 8) * HPAD * CDIM;
#pragma unroll
            for (int it = 0; it < 4; it++) {
                int idx = it * 256 + tid;
                int cl = idx >> 4;
                int h4 = (idx & 15) * 4;
                float4 v = live ? *(const float4*)(in + (size_t)(cb + cl) * HDIM + hb + h4)
                                : make_float4(0.f, 0.f, 0.f, 0.f);
                t[h4 + 0][cl] = v.x;
                t[h4 + 1][cl] = v.y;
                t[h4 + 2][cl] = v.z;
                t[h4 + 3][cl] = v.w;
            }
            __syncthreads();
#pragma unroll
            for (int it = 0; it < 2; it++) {
                int idx = it * 256 + tid;
                int hl = idx >> 3;
                int c8 = (idx & 7) * 8;
                u16x8 v;
#pragma unroll
                for (int j = 0; j < 8; j++) v[j] = f2bu(t[hl][c8 + j]);
                *(u16x8*)(out + (size_t)(hb + hl) * CDIM + cb + c8) = v;
            }
        } else {
            int e = zi - 16;
            const float* in = Wd + (size_t)e * HDIM * CDIM;
            u16* out = WdT + (size_t)e * CDIM * HPAD;
#pragma unroll
            for (int it = 0; it < 4; it++) {
                int idx = it * 256 + tid;
                int hl = idx >> 4;
                int c4 = (idx & 15) * 4;
                float4 v = live ? *(const float4*)(in + (size_t)(hb + hl) * CDIM + cb + c4)
                                : make_float4(0.f, 0.f, 0.f, 0.f);
                t[c4 + 0][hl] = v.x;
                t[c4 + 1][hl] = v.y;
                t[c4 + 2][hl] = v.z;
                t[c4 + 3][hl] = v.w;
            }
            __syncthreads();
#pragma unroll
            for (int it = 0; it < 2; it++) {
                int idx = it * 256 + tid;
                int cl = idx >> 3;
                int h8 = (idx & 7) * 8;
                u16x8 v;
#pragma unroll
                for (int j = 0; j < 8; j++) v[j] = f2bu(t[cl][h8 + j]);
                *(u16x8*)(out + (size_t)(cb + cl) * HPAD + hb + h8) = v;
            }
        }
    } else if (bz < 18944) {
        // ------- router -------
        __shared__ float s_me[8];
        __shared__ float s_z;
        __shared__ int s_ce[8];
        if (tid < 8) s_me[tid] = 0.f;
        if (tid == 8) s_z = 0.f;
        if (tid >= 16 && tid < 24) s_ce[tid - 16] = 0;
        __syncthreads();

        int wv = tid >> 6, lane = tid & 63;
        int tok = (bz - 16896) * 4 + wv;
        const float* xr = x + (size_t)tok * CDIM;

        float acc[8];
#pragma unroll
        for (int e = 0; e < 8; e++) acc[e] = 0.f;
#pragma unroll
        for (int j = 0; j < 16; j++) {
            int c = j * 64 + lane;
            float xv = xr[c];
            const float4 w0 = *(const float4*)(Wr + c * 8);
            const float4 w1 = *(const float4*)(Wr + c * 8 + 4);
            acc[0] = fmaf(xv, w0.x, acc[0]);
            acc[1] = fmaf(xv, w0.y, acc[1]);
            acc[2] = fmaf(xv, w0.z, acc[2]);
            acc[3] = fmaf(xv, w0.w, acc[3]);
            acc[4] = fmaf(xv, w1.x, acc[4]);
            acc[5] = fmaf(xv, w1.y, acc[5]);
            acc[6] = fmaf(xv, w1.z, acc[6]);
            acc[7] = fmaf(xv, w1.w, acc[7]);
        }
#pragma unroll
        for (int off = 32; off >= 1; off >>= 1) {
#pragma unroll
            for (int e = 0; e < 8; e++) acc[e] += __shfl_xor(acc[e], off, 64);
        }
        float mx = acc[0];
#pragma unroll
        for (int e = 1; e < 8; e++) mx = fmaxf(mx, acc[e]);
        float g[8];
        float se = 0.f;
#pragma unroll
        for (int e = 0; e < 8; e++) {
            g[e] = __expf(acc[e] - mx);
            se += g[e];
        }
        float inv = 1.f / se;
#pragma unroll
        for (int e = 0; e < 8; e++) g[e] *= inv;
        int i1 = 0;
#pragma unroll
        for (int e = 1; e < 8; e++)
            if (acc[e] > acc[i1]) i1 = e;
        int i2 = -1;
#pragma unroll
        for (int e = 0; e < 8; e++) {
            if (e == i1) continue;
            if (i2 < 0 || acc[e] > acc[i2]) i2 = e;
        }
        float zp = 0.f;
#pragma unroll
        for (int e = 0; e < 8; e++) zp = fmaf(acc[e], acc[e], zp);

        if (lane == 0) {
            top2i[tok * 2 + 0] = i1;
            top2i[tok * 2 + 1] = i2;
            top2v[tok * 2 + 0] = g[i1];
            top2v[tok * 2 + 1] = g[i2];
            atomicAdd(&s_z, zp);
            atomicAdd(&s_ce[i1], 1);
            atomicAdd(&blkCnt[(tok >> 8) * 16 + i1], 1);
            atomicAdd(&blkCnt[(tok >> 8) * 16 + 8 + i2], 1);
#pragma unroll
            for (int e = 0; e < 8; e++) atomicAdd(&s_me[e], g[e]);
        }
        __syncthreads();
        if (tid < 8) atomicAdd(&lossf[tid], s_me[tid]);
        if (tid == 8) atomicAdd(&lossf[8], s_z);
        if (tid >= 16 && tid < 24) atomicAdd(&ce[tid - 16], s_ce[tid - 16]);
    } else {
        // ------- zero out[0 .. NTOK*CDIM) -------
        int blk = bz - 18944;  // 0..1023
        float4* p = (float4*)(outz) + (size_t)blk * 2048 + tid;
        float4 z = make_float4(0.f, 0.f, 0.f, 0.f);
#pragma unroll
        for (int j = 0; j < 8; j++) p[j * 256] = z;
    }
}

// ---------------- K3: prefix over blocks + expert meta ----------------
__global__ void k_prefix(const int* __restrict__ blkCnt, int* __restrict__ blkBase,
                         int* __restrict__ meta) {
    int p = threadIdx.x;
    int run = 0;
    if (p < 16) {
        for (int b = 0; b < 32; b++) {
            int v = blkCnt[b * 16 + p];
            blkBase[b * 16 + p] = run;
            run += v;
        }
    }
    int kept = run < CAPQ ? run : CAPQ;
    int k0e[8], k1e[8];
#pragma unroll
    for (int e = 0; e < 8; e++) {
        k0e[e] = __shfl(kept, e, 64);
        k1e[e] = __shfl(kept, 8 + e, 64);
    }
    if (p == 0) {
        int acc = 0;
        for (int e = 0; e < 8; e++) {
            int m = k0e[e] + k1e[e];
            int mp = (m + 255) & ~255;
            meta[e] = k0e[e];
            meta[8 + e] = k1e[e];
            meta[16 + e] = m;
            meta[24 + e] = mp;
            meta[32 + e] = acc;
            acc += mp;
        }
        meta[40] = acc;
    }
}

// ---------------- K4: per-token FIFO position, row assignment -------------
__global__ __launch_bounds__(256) void k_assign(const int* __restrict__ top2i,
                                                const int* __restrict__ blkBase,
                                                const int* __restrict__ meta,
                                                int* __restrict__ rowTok) {
    __shared__ int wcnt[4][16];
    int tid = threadIdx.x, w = tid >> 6, lane = tid & 63;
    int i = blockIdx.x * 256 + tid;
    int e0 = top2i[2 * i], e1 = top2i[2 * i + 1];
    unsigned long long m0 = 0, m1 = 0;
#pragma unroll
    for (int ex = 0; ex < 8; ex++) {
        unsigned long long b0 = __ballot(e0 == ex);
        unsigned long long b1 = __ballot(e1 == ex);
        if (e0 == ex) m0 = b0;
        if (e1 == ex) m1 = b1;
        if (lane == ex) {
            wcnt[w][ex] = __popcll(b0);
            wcnt[w][8 + ex] = __popcll(b1);
        }
    }
    __syncthreads();
    unsigned long long lt = (1ull << lane) - 1ull;
    int pos0 = blkBase[blockIdx.x * 16 + e0] + __popcll(m0 & lt);
    int pos1 = blkBase[blockIdx.x * 16 + 8 + e1] + __popcll(m1 & lt);
    for (int w2 = 0; w2 < w; w2++) {
        pos0 += wcnt[w2][e0];
        pos1 += wcnt[w2][8 + e1];
    }
    if (pos0 < CAPQ) rowTok[meta[32 + e0] + pos0] = i;
    if (pos1 < CAPQ) rowTok[meta[32 + e1] + meta[e1] + pos1] = i;
}

// ---------------- K5: gather token rows -> compact A (bf16) ---------------
__global__ __launch_bounds__(256) void k_gather(const float* __restrict__ x,
                                                const int* __restrict__ meta,
                                                const int* __restrict__ rowTok,
                                                u16* __restrict__ A) {
    int row = blockIdx.x * 4 + (threadIdx.x >> 6);
    int lane = threadIdx.x & 63;
    if (row >= meta[40]) return;
    int e = 0;
#pragma unroll
    for (int t = 1; t < 8; t++)
        if (row >= meta[32 + t]) e = t;
    int r = row - meta[32 + e];
    u16* dst = A + (size_t)row * CDIM;
    if (r >= meta[16 + e]) {
        ushort4 zz = make_ushort4(0, 0, 0, 0);
#pragma unroll
        for (int j = 0; j < 4; j++) *(ushort4*)(dst + j * 256 + lane * 4) = zz;
        return;
    }
    int tok = rowTok[row];
    const float* src = x + (size_t)tok * CDIM;
#pragma unroll
    for (int j = 0; j < 4; j++) {
        int c = j * 256 + lane * 4;
        float4 v = *(const float4*)(src + c);
        ushort4 p = make_ushort4(f2bu(v.x), f2bu(v.y), f2bu(v.z), f2bu(v.w));
        *(ushort4*)(dst + c) = p;
    }
}

// ====== wave-slab 32x32x16 GEMMs, verified swizzle, T4 counted-vmcnt ======

// ---------------- K7: fused gate/up GEMM + SiLU*U -> hgu bf16 -------------
__global__ __launch_bounds__(512, 2) void k_gemm_gu(const u16* __restrict__ A,
                                                    const u16* __restrict__ Bg,
                                                    const u16* __restrict__ Bu,
                                                    u16* __restrict__ HGU,
                                                    const int* __restrict__ meta) {
    const int e = blockIdx.z;
    const int mPad = meta[24 + e];
    if ((int)(blockIdx.y * 256) >= mPad) return;
    const size_t row0 = (size_t)meta[32 + e] + (size_t)blockIdx.y * 256;
    const int col0 = blockIdx.x * 128;

    const u16* Ab = A + row0 * CDIM;
    const u16* Gb = Bg + ((size_t)e * HPAD + col0) * CDIM;
    const u16* Ub = Bu + ((size_t)e * HPAD + col0) * CDIM;

    __shared__ u16 sm[65536];
    u16* sA = sm;
    u16* sB = sm + 32768;

    const int tid = threadIdx.x;
    const int lane = tid & 63, w = tid >> 6;
    const int rg = w & 3, cg = w >> 2;
    const int l31 = lane & 31, sl2 = lane >> 5;
    const int sr8 = lane >> 3;
    int ph[4];
#pragma unroll
    for (int ks = 0; ks < 4; ks++)
        ph[ks] = (((ks * 2 + sl2) ^ (l31 & 7) ^ ((l31 >> 4) & 1)) * 8);
    const int aoff = (rg * 64 + l31) * 64;
    const int boff = (cg * 64 + l31) * 64;

    auto stage = [&](int buf, int t) {
#pragma unroll
        for (int j = 0; j < 4; ++j) {
            const int ca = w * 4 + j;
            const int swz = ((lane & 7) ^ sr8 ^ ((ca >> 1) & 1)) * 8;
            gl_lds16(Ab + (size_t)(8 * ca + sr8) * CDIM + t * 64 + swz,
                     sA + buf * 16384 + ca * 512);
        }
#pragma unroll
        for (int j = 0; j < 4; ++j) {
            const int cb = w * 4 + j;
            const int swz = ((lane & 7) ^ sr8 ^ ((cb >> 1) & 1)) * 8;
            const u16* src = (cb < 16)
                ? Gb + (size_t)(8 * cb + sr8) * CDIM
                : Ub + (size_t)(8 * cb - 128 + sr8) * CDIM;
            gl_lds16(src + t * 64 + swz, sB + buf * 16384 + cb * 512);
        }
    };

    f32x16 zz = {0.f, 0.f, 0.f, 0.f, 0.f, 0.f, 0.f, 0.f,
                 0.f, 0.f, 0.f, 0.f, 0.f, 0.f, 0.f, 0.f};
    f32x16 aG[2][2], aU[2][2];
#pragma unroll
    for (int mi = 0; mi < 2; mi++)
#pragma unroll
        for (int ni = 0; ni < 2; ni++) {
            aG[mi][ni] = zz;
            aU[mi][ni] = zz;
        }

    const int NT = CDIM / 64;  // 16
    stage(0, 0);
    stage(1, 1);
    for (int t = 0; t < NT; ++t) {
        const int p = t & 1;
        if (t < NT - 1) asm volatile("s_waitcnt vmcnt(8)" ::: "memory");
        else asm volatile("s_waitcnt vmcnt(0)" ::: "memory");
        __builtin_amdgcn_s_barrier();
        const u16* pA = sA + p * 16384;
        const u16* pB = sB + p * 16384;
        bf16x8 af[2][4];
#pragma unroll
        for (int mi = 0; mi < 2; mi++)
#pragma unroll
            for (int ks = 0; ks < 4; ks++)
                af[mi][ks] = *(const bf16x8*)(pA + aoff + mi * 2048 + ph[ks]);
#pragma unroll
        for (int ks = 0; ks < 4; ks++) {
            bf16x8 bg0 = *(const bf16x8*)(pB + boff + ph[ks]);
            bf16x8 bg1 = *(const bf16x8*)(pB + boff + 2048 + ph[ks]);
            bf16x8 bu0 = *(const bf16x8*)(pB + 8192 + boff + ph[ks]);
            bf16x8 bu1 = *(const bf16x8*)(pB + 8192 + boff + 2048 + ph[ks]);
#pragma unroll
            for (int mi = 0; mi < 2; mi++) {
                aG[mi][0] = __builtin_amdgcn_mfma_f32_32x32x16_bf16(af[mi][ks], bg0, aG[mi][0], 0, 0, 0);
                aG[mi][1] = __builtin_amdgcn_mfma_f32_32x32x16_bf16(af[mi][ks], bg1, aG[mi][1], 0, 0, 0);
                aU[mi][0] = __builtin_amdgcn_mfma_f32_32x32x16_bf16(af[mi][ks], bu0, aU[mi][0], 0, 0, 0);
                aU[mi][1] = __builtin_amdgcn_mfma_f32_32x32x16_bf16(af[mi][ks], bu1, aU[mi][1], 0, 0, 0);
            }
        }
        __builtin_amdgcn_s_barrier();
        if (t + 2 < NT) stage(p, t + 2);
    }

    u16* Ob = HGU + row0 * HPAD + col0;
    const int ro = rg * 64, co = cg * 64;
#pragma unroll
    for (int mi = 0; mi < 2; mi++)
#pragma unroll
        for (int ni = 0; ni < 2; ni++)
#pragma unroll
            for (int r = 0; r < 16; r++) {
                const int rr = ro + mi * 32 + (r & 3) + 8 * (r >> 2) + 4 * sl2;
                const int cc = co + ni * 32 + l31;
                float gg = aG[mi][ni][r];
                float uu = aU[mi][ni][r];
                float v = (gg / (1.f + __expf(-gg))) * uu;
                Ob[(size_t)rr * HPAD + cc] = f2bu(v);
            }
}

// ------- K8: down GEMM, BM=128 BN=128, fused weighted-combine epilogue ----
__global__ __launch_bounds__(512, 4) void k_gemm_d(const u16* __restrict__ HGU,
                                                   const u16* __restrict__ Bd,
                                                   float* __restrict__ out,
                                                   const int* __restrict__ meta,
                                                   const int* __restrict__ rowTok,
                                                   const float* __restrict__ top2v) {
    const int e = blockIdx.z;
    const int mPad = meta[24 + e];
    if ((int)(blockIdx.y * 128) >= mPad) return;
    const int rbase = blockIdx.y * 128;
    const size_t row0 = (size_t)meta[32 + e] + rbase;
    const int col0 = blockIdx.x * 128;
    const int kept0 = meta[e];
    const int mlive = meta[16 + e];

    const u16* Ab = HGU + row0 * HPAD;
    const u16* Bb = Bd + ((size_t)e * CDIM + col0) * HPAD;

    __shared__ u16 sm[32768];
    u16* sA = sm;
    u16* sB = sm + 16384;

    const int tid = threadIdx.x;
    const int lane = tid & 63, w = tid >> 6;
    const int rg = w & 3, cg = w >> 2;
    const int l31 = lane & 31, sl2 = lane >> 5;
    const int sr8 = lane >> 3;
    int ph[4];
#pragma unroll
    for (int ks = 0; ks < 4; ks++)
        ph[ks] = (((ks * 2 + sl2) ^ (l31 & 7) ^ ((l31 >> 4) & 1)) * 8);
    const int aoff = (rg * 32 + l31) * 64;
    const int boff = (cg * 64 + l31) * 64;

    auto stage = [&](int buf, int t) {
#pragma unroll
        for (int j = 0; j < 2; ++j) {
            const int ca = w * 2 + j;
            const int swz = ((lane & 7) ^ sr8 ^ ((ca >> 1) & 1)) * 8;
            gl_lds16(Ab + (size_t)(8 * ca + sr8) * HPAD + t * 64 + swz,
                     sA + buf * 8192 + ca * 512);
        }
#pragma unroll
        for (int j = 0; j < 2; ++j) {
            const int cb = w * 2 + j;
            const int swz = ((lane & 7) ^ sr8 ^ ((cb >> 1) & 1)) * 8;
            gl_lds16(Bb + (size_t)(8 * cb + sr8) * HPAD + t * 64 + swz,
                     sB + buf * 8192 + cb * 512);
        }
    };

    f32x16 zz = {0.f, 0.f, 0.f, 0.f, 0.f, 0.f, 0.f, 0.f,
                 0.f, 0.f, 0.f, 0.f, 0.f, 0.f, 0.f, 0.f};
    f32x16 aC[2];
    aC[0] = zz;
    aC[1] = zz;

    const int NT = HDIM / 64;  // 43 — pad K-tile contributes zeros
    stage(0, 0);
    stage(1, 1);
    for (int t = 0; t < NT; ++t) {
        const int p = t & 1;
        if (t < NT - 1) asm volatile("s_waitcnt vmcnt(4)" ::: "memory");
        else asm volatile("s_waitcnt vmcnt(0)" ::: "memory");
        __builtin_amdgcn_s_barrier();
        const u16* pA = sA + p * 8192;
        const u16* pB = sB + p * 8192;
        bf16x8 af[4];
#pragma unroll
        for (int ks = 0; ks < 4; ks++)
            af[ks] = *(const bf16x8*)(pA + aoff + ph[ks]);
#pragma unroll
        for (int ks = 0; ks < 4; ks++) {
            bf16x8 b0 = *(const bf16x8*)(pB + boff + ph[ks]);
            bf16x8 b1 = *(const bf16x8*)(pB + boff + 2048 + ph[ks]);
            aC[0] = __builtin_amdgcn_mfma_f32_32x32x16_bf16(af[ks], b0, aC[0], 0, 0, 0);
            aC[1] = __builtin_amdgcn_mfma_f32_32x32x16_bf16(af[ks], b1, aC[1], 0, 0, 0);
        }
        __builtin_amdgcn_s_barrier();
        if (t + 2 < NT) stage(p, t + 2);
    }

    const int ro = rg * 32, co = cg * 64;
#pragma unroll
    for (int r = 0; r < 16; r++) {
        const int rr = ro + (r & 3) + 8 * (r >> 2) + 4 * sl2;
        const int re = rbase + rr;
        if (re < mlive) {
            const int tok = rowTok[row0 + rr];
            const int k = (re >= kept0) ? 1 : 0;
            const float wgt = top2v[2 * tok + k];
            float* o = out + (size_t)tok * CDIM + col0 + co;
#pragma unroll
            for (int ni = 0; ni < 2; ni++)
                atomicAdd(o + ni * 32 + l31, wgt * aC[ni][r]);
        }
    }
}

// ---------------- K10: final scalar losses ----------------
__global__ void k_loss(const float* __restrict__ lossf, const int* __restrict__ ce,
                       float* __restrict__ out) {
    if (threadIdx.x == 0) {
        float aux = 0.f;
        for (int e = 0; e < 8; e++)
            aux += (lossf[e] / (float)NTOK) * ((float)ce[e] / (float)NTOK);
        aux *= (float)EXP;
        out[(size_t)NTOK * CDIM] = aux;
        out[(size_t)NTOK * CDIM + 1] = lossf[8] / (float)(NTOK * EXP);
    }
}

// ---------------- workspace layout ----------------
static constexpr size_t SZ_WT = (size_t)EXP * HPAD * CDIM * 2;
static constexpr size_t OFF_WGT = 0;
static constexpr size_t OFF_WUT = OFF_WGT + SZ_WT;
static constexpr size_t OFF_WDT = OFF_WUT + SZ_WT;
static constexpr size_t OFF_A = OFF_WDT + SZ_WT;
static constexpr size_t OFF_HGU = OFF_A + (size_t)MAXROWS * CDIM * 2;
static constexpr size_t OFF_T2I = OFF_HGU + (size_t)MAXROWS * HPAD * 2;
static constexpr size_t OFF_T2V = OFF_T2I + (size_t)NTOK * 2 * 4;
static constexpr size_t OFF_RTK = OFF_T2V + (size_t)NTOK * 2 * 4;
static constexpr size_t OFF_BC = OFF_RTK + (size_t)MAXROWS * 4;
static constexpr size_t OFF_BB = OFF_BC + 32 * 16 * 4;
static constexpr size_t OFF_MET = OFF_BB + 32 * 16 * 4;
static constexpr size_t OFF_LOSS = OFF_MET + 64 * 4;

extern "C" void kernel_launch(void* const* d_in, const int* in_sizes, int n_in,
                              void* d_out, int out_size, void* d_ws, size_t ws_size,
                              hipStream_t stream) {
    const float* x = (const float*)d_in[0];
    const float* Wr = (const float*)d_in[1];
    const float* Wg = (const float*)d_in[2];
    const float* Wu = (const float*)d_in[3];
    const float* Wd = (const float*)d_in[4];
    float* out = (float*)d_out;
    char* ws = (char*)d_ws;

    u16* WgT = (u16*)(ws + OFF_WGT);
    u16* WuT = (u16*)(ws + OFF_WUT);
    u16* WdT = (u16*)(ws + OFF_WDT);
    u16* Abuf = (u16*)(ws + OFF_A);
    u16* HGUb = (u16*)(ws + OFF_HGU);
    int* top2i = (int*)(ws + OFF_T2I);
    float* top2v = (float*)(ws + OFF_T2V);
    int* rowTok = (int*)(ws + OFF_RTK);
    int* blkCnt = (int*)(ws + OFF_BC);
    int* blkBase = (int*)(ws + OFF_BB);
    int* meta = (int*)(ws + OFF_MET);
    float* lossf = (float*)(ws + OFF_LOSS);
    int* ce = (int*)(ws + OFF_LOSS + 9 * 4);

    k_zero<<<1, 576, 0, stream>>>(lossf, blkCnt);
    k_front<<<19968, 256, 0, stream>>>(x, Wr, Wg, Wu, Wd, top2i, top2v, lossf, ce,
                                       blkCnt, WgT, WuT, WdT, out);
    k_prefix<<<1, 64, 0, stream>>>(blkCnt, blkBase, meta);
    k_assign<<<32, 256, 0, stream>>>(top2i, blkBase, meta, rowTok);
    k_gather<<<MAXROWS / 4, 256, 0, stream>>>(x, meta, rowTok, Abuf);
    k_gemm_gu<<<dim3(22, 20, 8), 512, 0, stream>>>(Abuf, WgT, WuT, HGUb, meta);
    k_gemm_d<<<dim3(8, 40, 8), 512, 0, stream>>>(HGUb, WdT, out, meta, rowTok, top2v);
    k_loss<<<1, 64, 0, stream>>>(lossf, ce, out);
}

// Round 20
// 555.854 us; speedup vs baseline: 1.0753x; 1.0040x over previous
//
#include <hip/hip_runtime.h>

typedef unsigned short u16;
typedef __attribute__((ext_vector_type(8))) short bf16x8;
typedef __attribute__((ext_vector_type(8))) unsigned short u16x8;
typedef __attribute__((ext_vector_type(16))) float f32x16;

#define NTOK 8192
#define CDIM 1024
#define EXP 8
#define HDIM 2752
#define HPAD 2816
#define CAPQ 2560
#define MAXROWS 18432

__device__ __forceinline__ u16 f2bu(float f) {
    unsigned u = __float_as_uint(f);
    u += 0x7fffu + ((u >> 16) & 1u);
    return (u16)(u >> 16);
}
__device__ __forceinline__ float b2f(u16 s) {
    return __uint_as_float(((unsigned)s) << 16);
}

__device__ __forceinline__ void gl_lds16(const u16* g, u16* l) {
    __builtin_amdgcn_global_load_lds(
        (const __attribute__((address_space(1))) unsigned int*)g,
        (__attribute__((address_space(3))) unsigned int*)l, 16, 0, 0);
}

// ---------------- K0: zero loss accumulators + blkCnt ----------------
__global__ void k_zero(float* p, int* blkCnt) {
    if (threadIdx.x < 32) p[threadIdx.x] = 0.f;
    int i = (int)threadIdx.x - 32;
    if (i >= 0 && i < 512) blkCnt[i] = 0;
}

// ---- K1: merged front: trans (0..16895) | router (16896..18943) | zero-out
__global__ __launch_bounds__(256) void k_front(const float* __restrict__ x,
                                               const float* __restrict__ Wr,
                                               const float* __restrict__ Wg,
                                               const float* __restrict__ Wu,
                                               const float* __restrict__ Wd,
                                               int* __restrict__ top2i,
                                               float* __restrict__ top2v,
                                               float* __restrict__ lossf,
                                               int* __restrict__ ce,
                                               int* __restrict__ blkCnt,
                                               u16* __restrict__ WgT,
                                               u16* __restrict__ WuT,
                                               u16* __restrict__ WdT,
                                               float* __restrict__ outz) {
    const int bz = blockIdx.x;
    const int tid = threadIdx.x;
    if (bz < 16896) {
        __shared__ float t[64][65];
        const int zi = bz / 704;
        const int rem = bz - zi * 704;
        const int hx = rem % 44, cy = rem / 44;
        const int hb = hx * 64, cb = cy * 64;
        const bool live = (hb < HDIM);
        if (zi < 16) {
            const float* in = (zi < 8) ? Wg + (size_t)zi * CDIM * HDIM
                                       : Wu + (size_t)(zi - 8) * CDIM * HDIM;
            u16* out = (zi < 8) ? WgT + (size_t)zi * HPAD * CDIM
                                : WuT + (size_t)(zi - 8) * HPAD * CDIM;
#pragma unroll
            for (int it = 0; it < 4; it++) {
                int idx = it * 256 + tid;
                int cl = idx >> 4;
                int h4 = (idx & 15) * 4;
                float4 v = live ? *(const float4*)(in + (size_t)(cb + cl) * HDIM + hb + h4)
                                : make_float4(0.f, 0.f, 0.f, 0.f);
                t[h4 + 0][cl] = v.x;
                t[h4 + 1][cl] = v.y;
                t[h4 + 2][cl] = v.z;
                t[h4 + 3][cl] = v.w;
            }
            __syncthreads();
#pragma unroll
            for (int it = 0; it < 2; it++) {
                int idx = it * 256 + tid;
                int hl = idx >> 3;
                int c8 = (idx & 7) * 8;
                u16x8 v;
#pragma unroll
                for (int j = 0; j < 8; j++) v[j] = f2bu(t[hl][c8 + j]);
                *(u16x8*)(out + (size_t)(hb + hl) * CDIM + cb + c8) = v;
            }
        } else {
            int e = zi - 16;
            const float* in = Wd + (size_t)e * HDIM * CDIM;
            u16* out = WdT + (size_t)e * CDIM * HPAD;
#pragma unroll
            for (int it = 0; it < 4; it++) {
                int idx = it * 256 + tid;
                int hl = idx >> 4;
                int c4 = (idx & 15) * 4;
                float4 v = live ? *(const float4*)(in + (size_t)(hb + hl) * CDIM + cb + c4)
                                : make_float4(0.f, 0.f, 0.f, 0.f);
                t[c4 + 0][hl] = v.x;
                t[c4 + 1][hl] = v.y;
                t[c4 + 2][hl] = v.z;
                t[c4 + 3][hl] = v.w;
            }
            __syncthreads();
#pragma unroll
            for (int it = 0; it < 2; it++) {
                int idx = it * 256 + tid;
                int cl = idx >> 3;
                int h8 = (idx & 7) * 8;
                u16x8 v;
#pragma unroll
                for (int j = 0; j < 8; j++) v[j] = f2bu(t[cl][h8 + j]);
                *(u16x8*)(out + (size_t)(cb + cl) * HPAD + hb + h8) = v;
            }
        }
    } else if (bz < 18944) {
        __shared__ float s_me[8];
        __shared__ float s_z;
        __shared__ int s_ce[8];
        if (tid < 8) s_me[tid] = 0.f;
        if (tid == 8) s_z = 0.f;
        if (tid >= 16 && tid < 24) s_ce[tid - 16] = 0;
        __syncthreads();

        int wv = tid >> 6, lane = tid & 63;
        int tok = (bz - 16896) * 4 + wv;
        const float* xr = x + (size_t)tok * CDIM;

        float acc[8];
#pragma unroll
        for (int e = 0; e < 8; e++) acc[e] = 0.f;
#pragma unroll
        for (int j = 0; j < 16; j++) {
            int c = j * 64 + lane;
            float xv = xr[c];
            const float4 w0 = *(const float4*)(Wr + c * 8);
            const float4 w1 = *(const float4*)(Wr + c * 8 + 4);
            acc[0] = fmaf(xv, w0.x, acc[0]);
            acc[1] = fmaf(xv, w0.y, acc[1]);
            acc[2] = fmaf(xv, w0.z, acc[2]);
            acc[3] = fmaf(xv, w0.w, acc[3]);
            acc[4] = fmaf(xv, w1.x, acc[4]);
            acc[5] = fmaf(xv, w1.y, acc[5]);
            acc[6] = fmaf(xv, w1.z, acc[6]);
            acc[7] = fmaf(xv, w1.w, acc[7]);
        }
#pragma unroll
        for (int off = 32; off >= 1; off >>= 1) {
#pragma unroll
            for (int e = 0; e < 8; e++) acc[e] += __shfl_xor(acc[e], off, 64);
        }
        float mx = acc[0];
#pragma unroll
        for (int e = 1; e < 8; e++) mx = fmaxf(mx, acc[e]);
        float g[8];
        float se = 0.f;
#pragma unroll
        for (int e = 0; e < 8; e++) {
            g[e] = __expf(acc[e] - mx);
            se += g[e];
        }
        float inv = 1.f / se;
#pragma unroll
        for (int e = 0; e < 8; e++) g[e] *= inv;
        int i1 = 0;
#pragma unroll
        for (int e = 1; e < 8; e++)
            if (acc[e] > acc[i1]) i1 = e;
        int i2 = -1;
#pragma unroll
        for (int e = 0; e < 8; e++) {
            if (e == i1) continue;
            if (i2 < 0 || acc[e] > acc[i2]) i2 = e;
        }
        float zp = 0.f;
#pragma unroll
        for (int e = 0; e < 8; e++) zp = fmaf(acc[e], acc[e], zp);

        if (lane == 0) {
            top2i[tok * 2 + 0] = i1;
            top2i[tok * 2 + 1] = i2;
            top2v[tok * 2 + 0] = g[i1];
            top2v[tok * 2 + 1] = g[i2];
            atomicAdd(&s_z, zp);
            atomicAdd(&s_ce[i1], 1);
            atomicAdd(&blkCnt[(tok >> 8) * 16 + i1], 1);
            atomicAdd(&blkCnt[(tok >> 8) * 16 + 8 + i2], 1);
#pragma unroll
            for (int e = 0; e < 8; e++) atomicAdd(&s_me[e], g[e]);
        }
        __syncthreads();
        if (tid < 8) atomicAdd(&lossf[tid], s_me[tid]);
        if (tid == 8) atomicAdd(&lossf[8], s_z);
        if (tid >= 16 && tid < 24) atomicAdd(&ce[tid - 16], s_ce[tid - 16]);
    } else {
        int blk = bz - 18944;
        float4* p = (float4*)(outz) + (size_t)blk * 2048 + tid;
        float4 z = make_float4(0.f, 0.f, 0.f, 0.f);
#pragma unroll
        for (int j = 0; j < 8; j++) p[j * 256] = z;
    }
}

// ---------------- K3: prefix over blocks + expert meta ----------------
__global__ void k_prefix(const int* __restrict__ blkCnt, int* __restrict__ blkBase,
                         int* __restrict__ meta) {
    int p = threadIdx.x;
    int run = 0;
    if (p < 16) {
        for (int b = 0; b < 32; b++) {
            int v = blkCnt[b * 16 + p];
            blkBase[b * 16 + p] = run;
            run += v;
        }
    }
    int kept = run < CAPQ ? run : CAPQ;
    int k0e[8], k1e[8];
#pragma unroll
    for (int e = 0; e < 8; e++) {
        k0e[e] = __shfl(kept, e, 64);
        k1e[e] = __shfl(kept, 8 + e, 64);
    }
    if (p == 0) {
        int acc = 0;
        for (int e = 0; e < 8; e++) {
            int m = k0e[e] + k1e[e];
            int mp = (m + 255) & ~255;
            meta[e] = k0e[e];
            meta[8 + e] = k1e[e];
            meta[16 + e] = m;
            meta[24 + e] = mp;
            meta[32 + e] = acc;
            acc += mp;
        }
        meta[40] = acc;
    }
}

// ---------------- K4: per-token FIFO position, row assignment -------------
__global__ __launch_bounds__(256) void k_assign(const int* __restrict__ top2i,
                                                const int* __restrict__ blkBase,
                                                const int* __restrict__ meta,
                                                int* __restrict__ rowTok) {
    __shared__ int wcnt[4][16];
    int tid = threadIdx.x, w = tid >> 6, lane = tid & 63;
    int i = blockIdx.x * 256 + tid;
    int e0 = top2i[2 * i], e1 = top2i[2 * i + 1];
    unsigned long long m0 = 0, m1 = 0;
#pragma unroll
    for (int ex = 0; ex < 8; ex++) {
        unsigned long long b0 = __ballot(e0 == ex);
        unsigned long long b1 = __ballot(e1 == ex);
        if (e0 == ex) m0 = b0;
        if (e1 == ex) m1 = b1;
        if (lane == ex) {
            wcnt[w][ex] = __popcll(b0);
            wcnt[w][8 + ex] = __popcll(b1);
        }
    }
    __syncthreads();
    unsigned long long lt = (1ull << lane) - 1ull;
    int pos0 = blkBase[blockIdx.x * 16 + e0] + __popcll(m0 & lt);
    int pos1 = blkBase[blockIdx.x * 16 + 8 + e1] + __popcll(m1 & lt);
    for (int w2 = 0; w2 < w; w2++) {
        pos0 += wcnt[w2][e0];
        pos1 += wcnt[w2][8 + e1];
    }
    if (pos0 < CAPQ) rowTok[meta[32 + e0] + pos0] = i;
    if (pos1 < CAPQ) rowTok[meta[32 + e1] + meta[e1] + pos1] = i;
}

// ---------------- K5: gather token rows -> compact A (bf16) ---------------
__global__ __launch_bounds__(256) void k_gather(const float* __restrict__ x,
                                                const int* __restrict__ meta,
                                                const int* __restrict__ rowTok,
                                                u16* __restrict__ A) {
    int row = blockIdx.x * 4 + (threadIdx.x >> 6);
    int lane = threadIdx.x & 63;
    if (row >= meta[40]) return;
    int e = 0;
#pragma unroll
    for (int t = 1; t < 8; t++)
        if (row >= meta[32 + t]) e = t;
    int r = row - meta[32 + e];
    u16* dst = A + (size_t)row * CDIM;
    if (r >= meta[16 + e]) {
        ushort4 zz = make_ushort4(0, 0, 0, 0);
#pragma unroll
        for (int j = 0; j < 4; j++) *(ushort4*)(dst + j * 256 + lane * 4) = zz;
        return;
    }
    int tok = rowTok[row];
    const float* src = x + (size_t)tok * CDIM;
#pragma unroll
    for (int j = 0; j < 4; j++) {
        int c = j * 256 + lane * 4;
        float4 v = *(const float4*)(src + c);
        ushort4 p = make_ushort4(f2bu(v.x), f2bu(v.y), f2bu(v.z), f2bu(v.w));
        *(ushort4*)(dst + c) = p;
    }
}

// ====== wave-slab 32x32x16 GEMMs, verified swizzle, T4 counted-vmcnt ======

// ---------------- K7: fused gate/up GEMM + SiLU*U -> hgu bf16 -------------
// Wave tile reshaped to 128 rows x {32 G | 32 U} (wm=w>>2, wn=w&3):
// 16 A + 8 B ds_reads per 32 MFMA = 0.75 KB/MFMA (was 1.5). LDS layout,
// staging, swizzle identical to r17.
__global__ __launch_bounds__(512, 2) void k_gemm_gu(const u16* __restrict__ A,
                                                    const u16* __restrict__ Bg,
                                                    const u16* __restrict__ Bu,
                                                    u16* __restrict__ HGU,
                                                    const int* __restrict__ meta) {
    const int e = blockIdx.z;
    const int mPad = meta[24 + e];
    if ((int)(blockIdx.y * 256) >= mPad) return;
    const size_t row0 = (size_t)meta[32 + e] + (size_t)blockIdx.y * 256;
    const int col0 = blockIdx.x * 128;

    const u16* Ab = A + row0 * CDIM;
    const u16* Gb = Bg + ((size_t)e * HPAD + col0) * CDIM;
    const u16* Ub = Bu + ((size_t)e * HPAD + col0) * CDIM;

    __shared__ u16 sm[65536];
    u16* sA = sm;
    u16* sB = sm + 32768;

    const int tid = threadIdx.x;
    const int lane = tid & 63, w = tid >> 6;
    const int wm = w >> 2, wn = w & 3;
    const int l31 = lane & 31, sl2 = lane >> 5;
    const int sr8 = lane >> 3;
    int ph[4];
#pragma unroll
    for (int ks = 0; ks < 4; ks++)
        ph[ks] = (((ks * 2 + sl2) ^ (l31 & 7) ^ ((l31 >> 4) & 1)) * 8);
    const int aoff = (wm * 128 + l31) * 64;
    const int boff = (wn * 32 + l31) * 64;

    auto stage = [&](int buf, int t) {
#pragma unroll
        for (int j = 0; j < 4; ++j) {
            const int ca = w * 4 + j;
            const int swz = ((lane & 7) ^ sr8 ^ ((ca >> 1) & 1)) * 8;
            gl_lds16(Ab + (size_t)(8 * ca + sr8) * CDIM + t * 64 + swz,
                     sA + buf * 16384 + ca * 512);
        }
#pragma unroll
        for (int j = 0; j < 4; ++j) {
            const int cb = w * 4 + j;
            const int swz = ((lane & 7) ^ sr8 ^ ((cb >> 1) & 1)) * 8;
            const u16* src = (cb < 16)
                ? Gb + (size_t)(8 * cb + sr8) * CDIM
                : Ub + (size_t)(8 * cb - 128 + sr8) * CDIM;
            gl_lds16(src + t * 64 + swz, sB + buf * 16384 + cb * 512);
        }
    };

    f32x16 zz = {0.f, 0.f, 0.f, 0.f, 0.f, 0.f, 0.f, 0.f,
                 0.f, 0.f, 0.f, 0.f, 0.f, 0.f, 0.f, 0.f};
    f32x16 aG[4], aU[4];
#pragma unroll
    for (int mi = 0; mi < 4; mi++) {
        aG[mi] = zz;
        aU[mi] = zz;
    }

    const int NT = CDIM / 64;  // 16
    stage(0, 0);
    stage(1, 1);
    for (int t = 0; t < NT; ++t) {
        const int p = t & 1;
        if (t < NT - 1) asm volatile("s_waitcnt vmcnt(8)" ::: "memory");
        else asm volatile("s_waitcnt vmcnt(0)" ::: "memory");
        __builtin_amdgcn_s_barrier();
        const u16* pA = sA + p * 16384;
        const u16* pB = sB + p * 16384;
#pragma unroll
        for (int ks = 0; ks < 4; ks++) {
            bf16x8 bg = *(const bf16x8*)(pB + boff + ph[ks]);
            bf16x8 bu = *(const bf16x8*)(pB + 8192 + boff + ph[ks]);
#pragma unroll
            for (int mi = 0; mi < 4; mi++) {
                bf16x8 af = *(const bf16x8*)(pA + aoff + mi * 2048 + ph[ks]);
                aG[mi] = __builtin_amdgcn_mfma_f32_32x32x16_bf16(af, bg, aG[mi], 0, 0, 0);
                aU[mi] = __builtin_amdgcn_mfma_f32_32x32x16_bf16(af, bu, aU[mi], 0, 0, 0);
            }
        }
        __builtin_amdgcn_s_barrier();
        if (t + 2 < NT) stage(p, t + 2);
    }

    u16* Ob = HGU + row0 * HPAD + col0;
    const int cc = wn * 32 + l31;
#pragma unroll
    for (int mi = 0; mi < 4; mi++)
#pragma unroll
        for (int r = 0; r < 16; r++) {
            const int rr = wm * 128 + mi * 32 + (r & 3) + 8 * (r >> 2) + 4 * sl2;
            float gg = aG[mi][r];
            float uu = aU[mi][r];
            float v = (gg / (1.f + __expf(-gg))) * uu;
            Ob[(size_t)rr * HPAD + cc] = f2bu(v);
        }
}

// ------- K8: down GEMM, BM=128 BN=128, fused weighted-combine epilogue ----
__global__ __launch_bounds__(512, 4) void k_gemm_d(const u16* __restrict__ HGU,
                                                   const u16* __restrict__ Bd,
                                                   float* __restrict__ out,
                                                   const int* __restrict__ meta,
                                                   const int* __restrict__ rowTok,
                                                   const float* __restrict__ top2v) {
    const int e = blockIdx.z;
    const int mPad = meta[24 + e];
    if ((int)(blockIdx.y * 128) >= mPad) return;
    const int rbase = blockIdx.y * 128;
    const size_t row0 = (size_t)meta[32 + e] + rbase;
    const int col0 = blockIdx.x * 128;
    const int kept0 = meta[e];
    const int mlive = meta[16 + e];

    const u16* Ab = HGU + row0 * HPAD;
    const u16* Bb = Bd + ((size_t)e * CDIM + col0) * HPAD;

    __shared__ u16 sm[32768];
    u16* sA = sm;
    u16* sB = sm + 16384;

    const int tid = threadIdx.x;
    const int lane = tid & 63, w = tid >> 6;
    const int rg = w & 3, cg = w >> 2;
    const int l31 = lane & 31, sl2 = lane >> 5;
    const int sr8 = lane >> 3;
    int ph[4];
#pragma unroll
    for (int ks = 0; ks < 4; ks++)
        ph[ks] = (((ks * 2 + sl2) ^ (l31 & 7) ^ ((l31 >> 4) & 1)) * 8);
    const int aoff = (rg * 32 + l31) * 64;
    const int boff = (cg * 64 + l31) * 64;

    auto stage = [&](int buf, int t) {
#pragma unroll
        for (int j = 0; j < 2; ++j) {
            const int ca = w * 2 + j;
            const int swz = ((lane & 7) ^ sr8 ^ ((ca >> 1) & 1)) * 8;
            gl_lds16(Ab + (size_t)(8 * ca + sr8) * HPAD + t * 64 + swz,
                     sA + buf * 8192 + ca * 512);
        }
#pragma unroll
        for (int j = 0; j < 2; ++j) {
            const int cb = w * 2 + j;
            const int swz = ((lane & 7) ^ sr8 ^ ((cb >> 1) & 1)) * 8;
            gl_lds16(Bb + (size_t)(8 * cb + sr8) * HPAD + t * 64 + swz,
                     sB + buf * 8192 + cb * 512);
        }
    };

    f32x16 zz = {0.f, 0.f, 0.f, 0.f, 0.f, 0.f, 0.f, 0.f,
                 0.f, 0.f, 0.f, 0.f, 0.f, 0.f, 0.f, 0.f};
    f32x16 aC[2];
    aC[0] = zz;
    aC[1] = zz;

    const int NT = HDIM / 64;  // 43 — pad K-tile contributes zeros
    stage(0, 0);
    stage(1, 1);
    for (int t = 0; t < NT; ++t) {
        const int p = t & 1;
        if (t < NT - 1) asm volatile("s_waitcnt vmcnt(4)" ::: "memory");
        else asm volatile("s_waitcnt vmcnt(0)" ::: "memory");
        __builtin_amdgcn_s_barrier();
        const u16* pA = sA + p * 8192;
        const u16* pB = sB + p * 8192;
        bf16x8 af[4];
#pragma unroll
        for (int ks = 0; ks < 4; ks++)
            af[ks] = *(const bf16x8*)(pA + aoff + ph[ks]);
#pragma unroll
        for (int ks = 0; ks < 4; ks++) {
            bf16x8 b0 = *(const bf16x8*)(pB + boff + ph[ks]);
            bf16x8 b1 = *(const bf16x8*)(pB + boff + 2048 + ph[ks]);
            aC[0] = __builtin_amdgcn_mfma_f32_32x32x16_bf16(af[ks], b0, aC[0], 0, 0, 0);
            aC[1] = __builtin_amdgcn_mfma_f32_32x32x16_bf16(af[ks], b1, aC[1], 0, 0, 0);
        }
        __builtin_amdgcn_s_barrier();
        if (t + 2 < NT) stage(p, t + 2);
    }

    const int ro = rg * 32, co = cg * 64;
#pragma unroll
    for (int r = 0; r < 16; r++) {
        const int rr = ro + (r & 3) + 8 * (r >> 2) + 4 * sl2;
        const int re = rbase + rr;
        if (re < mlive) {
            const int tok = rowTok[row0 + rr];
            const int k = (re >= kept0) ? 1 : 0;
            const float wgt = top2v[2 * tok + k];
            float* o = out + (size_t)tok * CDIM + col0 + co;
#pragma unroll
            for (int ni = 0; ni < 2; ni++)
                atomicAdd(o + ni * 32 + l31, wgt * aC[ni][r]);
        }
    }
}

// ---------------- K10: final scalar losses ----------------
__global__ void k_loss(const float* __restrict__ lossf, const int* __restrict__ ce,
                       float* __restrict__ out) {
    if (threadIdx.x == 0) {
        float aux = 0.f;
        for (int e = 0; e < 8; e++)
            aux += (lossf[e] / (float)NTOK) * ((float)ce[e] / (float)NTOK);
        aux *= (float)EXP;
        out[(size_t)NTOK * CDIM] = aux;
        out[(size_t)NTOK * CDIM + 1] = lossf[8] / (float)(NTOK * EXP);
    }
}

// ---------------- workspace layout ----------------
static constexpr size_t SZ_WT = (size_t)EXP * HPAD * CDIM * 2;
static constexpr size_t OFF_WGT = 0;
static constexpr size_t OFF_WUT = OFF_WGT + SZ_WT;
static constexpr size_t OFF_WDT = OFF_WUT + SZ_WT;
static constexpr size_t OFF_A = OFF_WDT + SZ_WT;
static constexpr size_t OFF_HGU = OFF_A + (size_t)MAXROWS * CDIM * 2;
static constexpr size_t OFF_T2I = OFF_HGU + (size_t)MAXROWS * HPAD * 2;
static constexpr size_t OFF_T2V = OFF_T2I + (size_t)NTOK * 2 * 4;
static constexpr size_t OFF_RTK = OFF_T2V + (size_t)NTOK * 2 * 4;
static constexpr size_t OFF_BC = OFF_RTK + (size_t)MAXROWS * 4;
static constexpr size_t OFF_BB = OFF_BC + 32 * 16 * 4;
static constexpr size_t OFF_MET = OFF_BB + 32 * 16 * 4;
static constexpr size_t OFF_LOSS = OFF_MET + 64 * 4;

extern "C" void kernel_launch(void* const* d_in, const int* in_sizes, int n_in,
                              void* d_out, int out_size, void* d_ws, size_t ws_size,
                              hipStream_t stream) {
    const float* x = (const float*)d_in[0];
    const float* Wr = (const float*)d_in[1];
    const float* Wg = (const float*)d_in[2];
    const float* Wu = (const float*)d_in[3];
    const float* Wd = (const float*)d_in[4];
    float* out = (float*)d_out;
    char* ws = (char*)d_ws;

    u16* WgT = (u16*)(ws + OFF_WGT);
    u16* WuT = (u16*)(ws + OFF_WUT);
    u16* WdT = (u16*)(ws + OFF_WDT);
    u16* Abuf = (u16*)(ws + OFF_A);
    u16* HGUb = (u16*)(ws + OFF_HGU);
    int* top2i = (int*)(ws + OFF_T2I);
    float* top2v = (float*)(ws + OFF_T2V);
    int* rowTok = (int*)(ws + OFF_RTK);
    int* blkCnt = (int*)(ws + OFF_BC);
    int* blkBase = (int*)(ws + OFF_BB);
    int* meta = (int*)(ws + OFF_MET);
    float* lossf = (float*)(ws + OFF_LOSS);
    int* ce = (int*)(ws + OFF_LOSS + 9 * 4);

    k_zero<<<1, 576, 0, stream>>>(lossf, blkCnt);
    k_front<<<19968, 256, 0, stream>>>(x, Wr, Wg, Wu, Wd, top2i, top2v, lossf, ce,
                                       blkCnt, WgT, WuT, WdT, out);
    k_prefix<<<1, 64, 0, stream>>>(blkCnt, blkBase, meta);
    k_assign<<<32, 256, 0, stream>>>(top2i, blkBase, meta, rowTok);
    k_gather<<<MAXROWS / 4, 256, 0, stream>>>(x, meta, rowTok, Abuf);
    k_gemm_gu<<<dim3(22, 20, 8), 512, 0, stream>>>(Abuf, WgT, WuT, HGUb, meta);
    k_gemm_d<<<dim3(8, 40, 8), 512, 0, stream>>>(HGUb, WdT, out, meta, rowTok, top2v);
    k_loss<<<1, 64, 0, stream>>>(lossf, ce, out);
}